// Round 6
// baseline (655.552 us; speedup 1.0000x reference)
//
#include <hip/hip_runtime.h>
#include <math.h>

// MinVQVAE1D forward. Phased (4-phase/K-step, 3-buffer, counted-vmcnt) MFMA
// GEMMs with XCD-swizzle + setprio. Split-bf16 encoder+scores, bf16 decoder.
// N=16384, D=1024, H=1024, L=256, K=4096.
// out = [x_pred (N*D) f32 | z_discrete 0/1 f32 (N*K) | loss (1)]

#define MB (1024ULL * 1024ULL)

typedef __attribute__((ext_vector_type(8))) short s16x8;
typedef __attribute__((ext_vector_type(4))) float f32x4;

__device__ __forceinline__ ushort f2bf(float f) {
    unsigned u = __float_as_uint(f);
    u += 0x7fffu + ((u >> 16) & 1u);
    return (ushort)(u >> 16);
}
__device__ __forceinline__ float bf2f(ushort h) {
    return __uint_as_float(((unsigned)h) << 16);
}
__device__ __forceinline__ float gelu_f(float v) {
    return 0.5f * v * (1.0f + erff(v * 0.70710678118654752f));
}
__device__ __forceinline__ void gload16(const void* g, void* l) {
    __builtin_amdgcn_global_load_lds(
        (const __attribute__((address_space(1))) void*)g,
        (__attribute__((address_space(3))) void*)l, 16, 0, 0);
}

// ---------------------------------------------------------------------------
// f32 [R][K] -> hilo-packed bf16: row stride 2K ushorts, per 32-k slab:
// [32 hi | 32 lo].
__global__ __launch_bounds__(256)
void split_pack(const float* __restrict__ in, ushort* __restrict__ out,
                int R, int K)
{
    const int nch = R * (K >> 3);
    for (int i = blockIdx.x * 256 + threadIdx.x; i < nch; i += gridDim.x * 256) {
        const int row = i / (K >> 3);
        const int k8 = (i - row * (K >> 3)) * 8;
        const float4 v0 = *(const float4*)(in + (size_t)row * K + k8);
        const float4 v1 = *(const float4*)(in + (size_t)row * K + k8 + 4);
        float f[8] = {v0.x, v0.y, v0.z, v0.w, v1.x, v1.y, v1.z, v1.w};
        ushort h[8], l[8];
        #pragma unroll
        for (int j = 0; j < 8; j++) {
            h[j] = f2bf(f[j]);
            l[j] = f2bf(f[j] - bf2f(h[j]));
        }
        size_t o = (size_t)row * 2 * K + ((k8 >> 5) << 6) + (k8 & 31);
        *(ushort4*)(out + o)      = make_ushort4(h[0], h[1], h[2], h[3]);
        *(ushort4*)(out + o + 4)  = make_ushort4(h[4], h[5], h[6], h[7]);
        *(ushort4*)(out + o + 32) = make_ushort4(l[0], l[1], l[2], l[3]);
        *(ushort4*)(out + o + 36) = make_ushort4(l[4], l[5], l[6], l[7]);
    }
}

// W [Kd, Nn] f32 -> out [Nn][Kd]; PACK -> hilo-packed, else plain bf16.
template<bool PACK>
__global__ __launch_bounds__(256)
void transpose_cvt(const float* __restrict__ in, ushort* __restrict__ out,
                   int Kd, int Nn)
{
    __shared__ float tile[32][33];
    const int n0 = blockIdx.x * 32, k0 = blockIdx.y * 32;
    const int tx = threadIdx.x & 31, ty = threadIdx.x >> 5;
    #pragma unroll
    for (int r = 0; r < 4; r++)
        tile[ty + r * 8][tx] = in[(size_t)(k0 + ty + r * 8) * Nn + n0 + tx];
    __syncthreads();
    #pragma unroll
    for (int r = 0; r < 4; r++) {
        const float v = tile[tx][ty + r * 8];
        const int row = n0 + ty + r * 8, k = k0 + tx;
        if constexpr (PACK) {
            size_t o = (size_t)row * 2 * Kd + ((k >> 5) << 6) + (k & 31);
            ushort h = f2bf(v);
            out[o] = h;
            out[o + 32] = f2bf(v - bf2f(h));
        } else {
            out[(size_t)row * Kd + k] = f2bf(v);
        }
    }
}

// ||e_k||^2 per codebook row (L=256)
__global__ __launch_bounds__(64)
void colnorm(const float* __restrict__ pool, float* __restrict__ c)
{
    int r = blockIdx.x, lane = threadIdx.x;
    float4 v = *(const float4*)(pool + (size_t)r * 256 + lane * 4);
    float s = v.x * v.x + v.y * v.y + v.z * v.z + v.w * v.w;
    #pragma unroll
    for (int o = 32; o > 0; o >>= 1) s += __shfl_down(s, o);
    if (lane == 0) c[r] = s;
}

// ---------------------------------------------------------------------------
// Phased pipelined MFMA GEMM: C[M,Nn] = A[M,Kd] @ B^T, B given as [Nn,Kd].
// Tile TM x 128, 512 threads (8 waves). TM=256: waves 4x2 (wave 64x64);
// TM=128: waves 2x4 (wave 64x32). 3 LDS buffers, distance-2 prefetch,
// counted s_waitcnt vmcnt(N) + raw s_barrier. Each K-step = 4 quadrant
// phases {ds_read subtile | stage part -> bar -> MFMA quadrant -> bar}.
// XCD-bijective block swizzle (nwg % 8 == 0 on all launches).
// SPLIT: BK=32 hilo slab; plain: BK=64.
// EPI: 0=+bias, 1=gelu(+bias), 2=sigmoid(+bias)+SSE, 3=VQ argmin partials.
template<int EPI, bool SPLIT, bool PACKOUT, int TM>
__global__ __launch_bounds__(512, 2)
void gemm_pipe(const ushort* __restrict__ A, const ushort* __restrict__ B,
               const float* __restrict__ bias, int Kd, int Nn,
               int rsA, int rsB,                    // row strides in BYTES
               ushort* __restrict__ Cu, float* __restrict__ Cf,
               const float* __restrict__ xref, float* __restrict__ ssePartial,
               float* __restrict__ pval, int* __restrict__ pidx)
{
    extern __shared__ ushort smem[];
    constexpr int AN   = (TM == 256) ? 4 : 2;       // n-fragments per wave
    constexpr int NQ   = AN / 2;                    // n-frags per phase
    constexpr int WCT  = (TM == 256) ? 64 : 32;     // wave column tile
    constexpr int ROWS = TM + 128;                  // LDS rows per buffer
    constexpr int BUFS = ROWS * 64;                 // ushorts per buffer

    const int tid = threadIdx.x;
    const int wave = tid >> 6, lane = tid & 63;

    // XCD-bijective swizzle (nwg % 8 == 0): XCD x owns contiguous tile range.
    const int nx = gridDim.x;
    const int nwg = nx * gridDim.y;
    const int orig = blockIdx.y * nx + blockIdx.x;
    const int wgid = (orig & 7) * (nwg >> 3) + (orig >> 3);
    const int bx = wgid % nx, by = wgid / nx;

    const int m0 = by * TM, n0 = bx * 128;
    const int wr = (TM == 256) ? (wave >> 1) : (wave >> 2);
    const int wc = (TM == 256) ? (wave & 1) : (wave & 3);
    const int fcol = lane & 15, kgrp = lane >> 4;
    const int NT = Kd / (SPLIT ? 32 : 64);

    const int srow = lane >> 3;                     // row within 8-row chunk
    const int sswz = ((lane & 7) ^ srow) << 4;      // swizzled src byte
    const char* Abase = (const char*)A + (size_t)m0 * rsA;
    const char* Bbase = (const char*)B + (size_t)n0 * rsB;

    f32x4 acc[4][AN];
    #pragma unroll
    for (int m = 0; m < 4; m++)
        #pragma unroll
        for (int n = 0; n < AN; n++)
            acc[m][n] = (f32x4){0.f, 0.f, 0.f, 0.f};

    // stage part: TM=256: 0 -> A rows 0..127, 1 -> A rows 128..255, 2 -> B.
    //             TM=128: 0 -> A, 1 -> B.
    auto STAGE_P = [&](int buf, int t, int part) {
        ushort* dst = smem + buf * BUFS;
        const size_t kb = (size_t)t * 128;
        if (part == 0) {
            #pragma unroll
            for (int g = 0; g < 2; g++) {
                const int rb = g * 64 + wave * 8;
                gload16(Abase + (size_t)(rb + srow) * rsA + kb + sswz, dst + rb * 64);
            }
        } else if (part == 1) {
            if constexpr (TM == 256) {
                #pragma unroll
                for (int g = 2; g < 4; g++) {
                    const int rb = g * 64 + wave * 8;
                    gload16(Abase + (size_t)(rb + srow) * rsA + kb + sswz, dst + rb * 64);
                }
            } else {
                #pragma unroll
                for (int g = 0; g < 2; g++) {
                    const int rb = g * 64 + wave * 8;
                    gload16(Bbase + (size_t)(rb + srow) * rsB + kb + sswz,
                            dst + (TM + rb) * 64);
                }
            }
        } else {
            #pragma unroll
            for (int g = 0; g < 2; g++) {
                const int rb = g * 64 + wave * 8;
                gload16(Bbase + (size_t)(rb + srow) * rsB + kb + sswz,
                        dst + (TM + rb) * 64);
            }
        }
    };
    auto STAGE_ALL = [&](int buf, int t) {
        STAGE_P(buf, t, 0);
        STAGE_P(buf, t, 1);
        if constexpr (TM == 256) STAGE_P(buf, t, 2);
    };
    auto LD = [&](int buf, int r, int u) -> s16x8 {
        return *(const s16x8*)(smem + buf * BUFS + r * 64 + ((u ^ (r & 7)) << 3));
    };
    auto rdA = [&](int buf, int m, int u) -> s16x8 {
        return LD(buf, wr * 64 + m * 16 + fcol, u);
    };
    auto rdB = [&](int buf, int n, int u) -> s16x8 {
        return LD(buf, TM + wc * WCT + n * 16 + fcol, u);
    };

    STAGE_ALL(0, 0);
    STAGE_ALL(1, 1);
    for (int t = 0; t < NT; ++t) {
        if (t + 1 < NT) {
            if constexpr (TM == 256) asm volatile("s_waitcnt vmcnt(6)" ::: "memory");
            else                     asm volatile("s_waitcnt vmcnt(4)" ::: "memory");
        } else {
            asm volatile("s_waitcnt vmcnt(0)" ::: "memory");
        }
        __builtin_amdgcn_s_barrier();
        const int buf = t % 3;
        const int nb = (t + 2) % 3;
        const bool st = (t + 2 < NT);

        if constexpr (SPLIT) {
            s16x8 aH[4], aL[4], bH[AN], bL[AN];
#define MFMA3Q(MOFF, NOFF)                                                     \
    __builtin_amdgcn_s_setprio(1);                                             \
    _Pragma("unroll")                                                          \
    for (int mq = 0; mq < 2; mq++) {                                           \
        _Pragma("unroll")                                                      \
        for (int nq = 0; nq < NQ; nq++) {                                      \
            acc[MOFF + mq][NOFF + nq] = __builtin_amdgcn_mfma_f32_16x16x32_bf16(\
                aH[MOFF + mq], bH[NOFF + nq], acc[MOFF + mq][NOFF + nq], 0, 0, 0);\
            acc[MOFF + mq][NOFF + nq] = __builtin_amdgcn_mfma_f32_16x16x32_bf16(\
                aH[MOFF + mq], bL[NOFF + nq], acc[MOFF + mq][NOFF + nq], 0, 0, 0);\
            acc[MOFF + mq][NOFF + nq] = __builtin_amdgcn_mfma_f32_16x16x32_bf16(\
                aL[MOFF + mq], bH[NOFF + nq], acc[MOFF + mq][NOFF + nq], 0, 0, 0);\
        }                                                                      \
    }                                                                          \
    __builtin_amdgcn_s_setprio(0);
            // phase 0: a01 + b[0..NQ)
            #pragma unroll
            for (int m = 0; m < 2; m++) { aH[m] = rdA(buf, m, kgrp); aL[m] = rdA(buf, m, 4 + kgrp); }
            #pragma unroll
            for (int n = 0; n < NQ; n++) { bH[n] = rdB(buf, n, kgrp); bL[n] = rdB(buf, n, 4 + kgrp); }
            if (st) STAGE_P(nb, t + 2, 0);
            __builtin_amdgcn_s_barrier();
            MFMA3Q(0, 0);
            __builtin_amdgcn_s_barrier();
            // phase 1: b[NQ..2NQ)
            #pragma unroll
            for (int n = NQ; n < 2 * NQ; n++) { bH[n] = rdB(buf, n, kgrp); bL[n] = rdB(buf, n, 4 + kgrp); }
            if (st) STAGE_P(nb, t + 2, 1);
            __builtin_amdgcn_s_barrier();
            MFMA3Q(0, NQ);
            __builtin_amdgcn_s_barrier();
            // phase 2: a23
            #pragma unroll
            for (int m = 2; m < 4; m++) { aH[m] = rdA(buf, m, kgrp); aL[m] = rdA(buf, m, 4 + kgrp); }
            if constexpr (TM == 256) { if (st) STAGE_P(nb, t + 2, 2); }
            __builtin_amdgcn_s_barrier();
            MFMA3Q(2, 0);
            __builtin_amdgcn_s_barrier();
            // phase 3: no reads
            MFMA3Q(2, NQ);
#undef MFMA3Q
        } else {
            s16x8 a2[4][2], b2[AN][2];
#define MFMAPQ(MOFF, NOFF)                                                     \
    __builtin_amdgcn_s_setprio(1);                                             \
    _Pragma("unroll")                                                          \
    for (int mq = 0; mq < 2; mq++) {                                           \
        _Pragma("unroll")                                                      \
        for (int nq = 0; nq < NQ; nq++) {                                      \
            _Pragma("unroll")                                                  \
            for (int ks = 0; ks < 2; ks++)                                     \
                acc[MOFF + mq][NOFF + nq] = __builtin_amdgcn_mfma_f32_16x16x32_bf16(\
                    a2[MOFF + mq][ks], b2[NOFF + nq][ks],                      \
                    acc[MOFF + mq][NOFF + nq], 0, 0, 0);                       \
        }                                                                      \
    }                                                                          \
    __builtin_amdgcn_s_setprio(0);
            // phase 0: a01 + b[0..NQ)
            #pragma unroll
            for (int m = 0; m < 2; m++)
                #pragma unroll
                for (int ks = 0; ks < 2; ks++) a2[m][ks] = rdA(buf, m, ks * 4 + kgrp);
            #pragma unroll
            for (int n = 0; n < NQ; n++)
                #pragma unroll
                for (int ks = 0; ks < 2; ks++) b2[n][ks] = rdB(buf, n, ks * 4 + kgrp);
            if (st) STAGE_P(nb, t + 2, 0);
            __builtin_amdgcn_s_barrier();
            MFMAPQ(0, 0);
            __builtin_amdgcn_s_barrier();
            // phase 1: b[NQ..2NQ)
            #pragma unroll
            for (int n = NQ; n < 2 * NQ; n++)
                #pragma unroll
                for (int ks = 0; ks < 2; ks++) b2[n][ks] = rdB(buf, n, ks * 4 + kgrp);
            if (st) STAGE_P(nb, t + 2, 1);
            __builtin_amdgcn_s_barrier();
            MFMAPQ(0, NQ);
            __builtin_amdgcn_s_barrier();
            // phase 2: a23
            #pragma unroll
            for (int m = 2; m < 4; m++)
                #pragma unroll
                for (int ks = 0; ks < 2; ks++) a2[m][ks] = rdA(buf, m, ks * 4 + kgrp);
            if constexpr (TM == 256) { if (st) STAGE_P(nb, t + 2, 2); }
            __builtin_amdgcn_s_barrier();
            MFMAPQ(2, 0);
            __builtin_amdgcn_s_barrier();
            // phase 3
            MFMAPQ(2, NQ);
#undef MFMAPQ
        }
    }
    __builtin_amdgcn_sched_barrier(0);

    // ------------------------------ epilogue ------------------------------
    int colg[AN];
    float bcol[AN];
    #pragma unroll
    for (int n = 0; n < AN; n++) {
        colg[n] = n0 + wc * WCT + n * 16 + fcol;
        bcol[n] = bias[colg[n]];
    }

    if constexpr (EPI == 0 || EPI == 1) {
        #pragma unroll
        for (int m = 0; m < 4; m++)
            #pragma unroll
            for (int v = 0; v < 4; v++) {
                const int row = m0 + wr * 64 + m * 16 + kgrp * 4 + v;
                #pragma unroll
                for (int n = 0; n < AN; n++) {
                    float val = acc[m][n][v] + bcol[n];
                    if (EPI == 1) val = gelu_f(val);
                    if constexpr (PACKOUT) {
                        size_t o = (size_t)row * 2 * Nn + ((colg[n] >> 5) << 6) + (colg[n] & 31);
                        ushort h = f2bf(val);
                        Cu[o] = h;
                        Cu[o + 32] = f2bf(val - bf2f(h));
                    } else {
                        Cu[(size_t)row * Nn + colg[n]] = f2bf(val);
                    }
                }
            }
    } else if constexpr (EPI == 2) {
        float lsse = 0.0f;
        #pragma unroll
        for (int m = 0; m < 4; m++)
            #pragma unroll
            for (int v = 0; v < 4; v++) {
                const int row = m0 + wr * 64 + m * 16 + kgrp * 4 + v;
                const size_t rb = (size_t)row * Nn;
                #pragma unroll
                for (int n = 0; n < AN; n++) {
                    float val = acc[m][n][v] + bcol[n];
                    val = 1.0f / (1.0f + expf(-val));
                    __builtin_nontemporal_store(val, &Cf[rb + colg[n]]);
                    float d = xref[rb + colg[n]] - val;
                    lsse += d * d;
                }
            }
        __syncthreads();
        float* red = (float*)smem;
        red[tid] = lsse;
        __syncthreads();
        for (int s = 256; s > 0; s >>= 1) {
            if (tid < s) red[tid] += red[tid + s];
            __syncthreads();
        }
        if (tid == 0) ssePartial[by * gridDim.x + bx] = red[0];
    } else if constexpr (EPI == 3) {
        __syncthreads();
        float* sv = (float*)smem;            // [2][256]
        int*   si = (int*)(sv + 512);
        #pragma unroll
        for (int m = 0; m < 4; m++)
            #pragma unroll
            for (int v = 0; v < 4; v++) {
                float best = INFINITY;
                int bidx = 0x7fffffff;
                #pragma unroll
                for (int n = 0; n < AN; n++) {
                    float sc = bcol[n] - 2.0f * acc[m][n][v];
                    if (sc < best || (sc == best && colg[n] < bidx)) { best = sc; bidx = colg[n]; }
                }
                #pragma unroll
                for (int d = 1; d < 16; d <<= 1) {
                    float ov = __shfl_xor(best, d, 64);
                    int   oi = __shfl_xor(bidx, d, 64);
                    if (ov < best || (ov == best && oi < bidx)) { best = ov; bidx = oi; }
                }
                if (fcol == 0) {
                    const int rl = wr * 64 + m * 16 + kgrp * 4 + v;
                    sv[wc * 256 + rl] = best;
                    si[wc * 256 + rl] = bidx;
                }
            }
        __syncthreads();
        if (tid < 256) {
            float v0 = sv[tid], v1 = sv[256 + tid];
            int   i0 = si[tid], i1 = si[256 + tid];
            if (v1 < v0 || (v1 == v0 && i1 < i0)) { v0 = v1; i0 = i1; }
            pval[(size_t)(m0 + tid) * gridDim.x + bx] = v0;
            pidx[(size_t)(m0 + tid) * gridDim.x + bx] = i0;
        }
    }
}

// ---------------------------------------------------------------------------
// 4 rows per block: reduce 32 block partials -> kbest; one-hot (nontemporal);
// gather z_q; VQ partial.
__global__ __launch_bounds__(256)
void argmin_final(const float* __restrict__ pval, const int* __restrict__ pidx,
                  int nblk, const ushort* __restrict__ zEp,
                  const float* __restrict__ pool,
                  float* __restrict__ zdisc, ushort* __restrict__ zq,
                  float* __restrict__ vqP)
{
    const int t = threadIdx.x;
    const int r = blockIdx.x * 4 + (t >> 6);
    const int l = t & 63;

    float best = INFINITY;
    int bi = 0x7fffffff;
    if (l < nblk) {
        best = pval[(size_t)r * nblk + l];
        bi = pidx[(size_t)r * nblk + l];
    }
    #pragma unroll
    for (int d = 32; d > 0; d >>= 1) {
        float ov = __shfl_xor(best, d, 64);
        int   oi = __shfl_xor(bi, d, 64);
        if (ov < best || (ov == best && oi < bi)) { best = ov; bi = oi; }
    }
    const int kbest = bi;

    f32x4* zrow = (f32x4*)(zdisc + (size_t)r * 4096);
    #pragma unroll
    for (int it = 0; it < 16; it++) {
        const int j = it * 64 + l;
        f32x4 o = (f32x4){0.f, 0.f, 0.f, 0.f};
        if ((kbest >> 2) == j) o[kbest & 3] = 1.0f;
        __builtin_nontemporal_store(o, &zrow[j]);
    }

    const float4 pz = *(const float4*)(pool + (size_t)kbest * 256 + l * 4);
    *(ushort4*)(zq + (size_t)r * 256 + l * 4) =
        make_ushort4(f2bf(pz.x), f2bf(pz.y), f2bf(pz.z), f2bf(pz.w));
    const size_t zo = (size_t)r * 512 + (((l * 4) >> 5) << 6) + ((l * 4) & 31);
    const ushort4 zh = *(const ushort4*)(zEp + zo);
    const ushort4 zl = *(const ushort4*)(zEp + zo + 32);
    float d0 = bf2f(zh.x) + bf2f(zl.x) - pz.x;
    float d1 = bf2f(zh.y) + bf2f(zl.y) - pz.y;
    float d2 = bf2f(zh.z) + bf2f(zl.z) - pz.z;
    float d3 = bf2f(zh.w) + bf2f(zl.w) - pz.w;
    float s = d0 * d0 + d1 * d1 + d2 * d2 + d3 * d3;
    #pragma unroll
    for (int o = 32; o > 0; o >>= 1) s += __shfl_xor(s, o, 64);
    if (l == 0) vqP[r] = s;
}

__global__ __launch_bounds__(256)
void loss_final(const float* __restrict__ sseP, int nP,
                const float* __restrict__ vqP, int nV,
                float* __restrict__ out)
{
    int tid = threadIdx.x;
    float sx = 0.0f, svq = 0.0f;
    for (int i = tid; i < nP; i += 256) sx += sseP[i];
    for (int i = tid; i < nV; i += 256) svq += vqP[i];
    __shared__ float a[256], b[256];
    a[tid] = sx; b[tid] = svq;
    __syncthreads();
    for (int s = 128; s > 0; s >>= 1) {
        if (tid < s) { a[tid] += a[tid + s]; b[tid] += b[tid + s]; }
        __syncthreads();
    }
    if (tid == 0) out[0] = (a[0] + 1.25f * b[0]) / 16384.0f;
}

// ---------------------------------------------------------------------------
extern "C" void kernel_launch(void* const* d_in, const int* in_sizes, int n_in,
                              void* d_out, int out_size, void* d_ws, size_t ws_size,
                              hipStream_t stream)
{
    const float* x    = (const float*)d_in[0];
    const float* pool = (const float*)d_in[1];
    const float* ew1  = (const float*)d_in[2];
    const float* eb1  = (const float*)d_in[3];
    const float* ew2  = (const float*)d_in[4];
    const float* eb2  = (const float*)d_in[5];
    const float* ew3  = (const float*)d_in[6];
    const float* eb3  = (const float*)d_in[7];
    const float* dw1  = (const float*)d_in[8];
    const float* db1  = (const float*)d_in[9];
    const float* dw2  = (const float*)d_in[10];
    const float* db2  = (const float*)d_in[11];
    const float* dw3  = (const float*)d_in[12];
    const float* db3  = (const float*)d_in[13];

    const int N = 16384, D = 1024, H = 1024, L = 256, K = 4096;

    float* out   = (float*)d_out;
    float* xpred = out;
    float* zdisc = out + (size_t)N * D;
    float* lossp = zdisc + (size_t)N * K;

    char* ws = (char*)d_ws;
    ushort* xp    = (ushort*)(ws + 0 * MB);    // 64MB packed x
    ushort* h1p   = (ushort*)(ws + 64 * MB);   // 64MB
    ushort* h2p   = (ushort*)(ws + 128 * MB);  // 64MB
    ushort* zEp   = (ushort*)(ws + 192 * MB);  // 16MB
    ushort* zq    = (ushort*)(ws + 208 * MB);  // 8MB plain bf16
    ushort* poolp = (ushort*)(ws + 216 * MB);  // 4MB
    ushort* w1p   = (ushort*)(ws + 220 * MB);  // 4MB
    ushort* w2p   = (ushort*)(ws + 224 * MB);  // 4MB
    ushort* w3p   = (ushort*)(ws + 228 * MB);  // 1MB
    ushort* v1    = (ushort*)(ws + 229 * MB);  // 0.5MB plain
    ushort* v2    = (ushort*)(ws + 230 * MB);  // 2MB
    ushort* v3    = (ushort*)(ws + 232 * MB);  // 2MB
    ushort* h3    = (ushort*)(ws + 240 * MB);  // 32MB plain
    ushort* h4    = (ushort*)(ws + 272 * MB);  // 32MB
    float*  cn    = (float*)(ws + 304 * MB);   // 16KB
    float*  pv    = (float*)(ws + 305 * MB);   // 2MB
    int*    pi    = (int*)(ws + 307 * MB);     // 2MB
    float*  vqP   = (float*)(ws + 309 * MB);   // 64KB
    float*  sxP   = (float*)(ws + 310 * MB);   // 4KB

    const int SH256 = 3 * (384 * 64) * 2;      // 147456 B
    const int SH128 = 3 * (256 * 64) * 2;      // 98304 B
    (void)hipFuncSetAttribute((const void*)gemm_pipe<1, true, true, 256>,
        hipFuncAttributeMaxDynamicSharedMemorySize, SH256);
    (void)hipFuncSetAttribute((const void*)gemm_pipe<0, true, true, 128>,
        hipFuncAttributeMaxDynamicSharedMemorySize, SH128);
    (void)hipFuncSetAttribute((const void*)gemm_pipe<3, true, false, 256>,
        hipFuncAttributeMaxDynamicSharedMemorySize, SH256);
    (void)hipFuncSetAttribute((const void*)gemm_pipe<1, false, false, 256>,
        hipFuncAttributeMaxDynamicSharedMemorySize, SH256);
    (void)hipFuncSetAttribute((const void*)gemm_pipe<2, false, false, 256>,
        hipFuncAttributeMaxDynamicSharedMemorySize, SH256);

    dim3 blk(256), gblk(512);

    // prep
    split_pack<<<2048, blk, 0, stream>>>(x, xp, N, D);
    split_pack<<<512, blk, 0, stream>>>(pool, poolp, K, L);
    colnorm<<<K, 64, 0, stream>>>(pool, cn);
    transpose_cvt<true><<<dim3(H / 32, D / 32), blk, 0, stream>>>(ew1, w1p, D, H);
    transpose_cvt<true><<<dim3(H / 32, H / 32), blk, 0, stream>>>(ew2, w2p, H, H);
    transpose_cvt<true><<<dim3(L / 32, H / 32), blk, 0, stream>>>(ew3, w3p, H, L);
    transpose_cvt<false><<<dim3(H / 32, L / 32), blk, 0, stream>>>(dw1, v1, L, H);
    transpose_cvt<false><<<dim3(H / 32, H / 32), blk, 0, stream>>>(dw2, v2, H, H);
    transpose_cvt<false><<<dim3(D / 32, H / 32), blk, 0, stream>>>(dw3, v3, H, D);

    // encoder (split, packed in/out)
    gemm_pipe<1, true, true, 256><<<dim3(H / 128, N / 256), gblk, SH256, stream>>>(
        xp, w1p, eb1, D, H, 2 * D * 2, 2 * D * 2, h1p, nullptr, nullptr, nullptr, nullptr, nullptr);
    gemm_pipe<1, true, true, 256><<<dim3(H / 128, N / 256), gblk, SH256, stream>>>(
        h1p, w2p, eb2, H, H, 2 * H * 2, 2 * H * 2, h2p, nullptr, nullptr, nullptr, nullptr, nullptr);
    // enc3: TM=128 -> 256 blocks (full GPU)
    gemm_pipe<0, true, true, 128><<<dim3(L / 128, N / 128), gblk, SH128, stream>>>(
        h2p, w3p, eb3, H, L, 2 * H * 2, 2 * H * 2, zEp, nullptr, nullptr, nullptr, nullptr, nullptr);

    // VQ scores + fused per-block argmin (split)
    gemm_pipe<3, true, false, 256><<<dim3(K / 128, N / 256), gblk, SH256, stream>>>(
        zEp, poolp, cn, L, K, 2 * L * 2, 2 * L * 2, nullptr, nullptr, nullptr, nullptr, pv, pi);

    argmin_final<<<N / 4, blk, 0, stream>>>(pv, pi, K / 128, zEp, pool, zdisc, zq, vqP);

    // decoder (plain bf16)
    gemm_pipe<1, false, false, 256><<<dim3(H / 128, N / 256), gblk, SH256, stream>>>(
        zq, v1, db1, L, H, L * 2, L * 2, h3, nullptr, nullptr, nullptr, nullptr, nullptr);
    gemm_pipe<1, false, false, 256><<<dim3(H / 128, N / 256), gblk, SH256, stream>>>(
        h3, v2, db2, H, H, H * 2, H * 2, h4, nullptr, nullptr, nullptr, nullptr, nullptr);
    gemm_pipe<2, false, false, 256><<<dim3(D / 128, N / 256), gblk, SH256, stream>>>(
        h4, v3, db3, H, D, H * 2, H * 2, nullptr, xpred, x, sxP, nullptr, nullptr);

    loss_final<<<1, blk, 0, stream>>>(sxP, (D / 128) * (N / 256), vqP, N, lossp);
}

// Round 7
// 599.385 us; speedup vs baseline: 1.0937x; 1.0937x over previous
//
#include <hip/hip_runtime.h>
#include <math.h>

// MinVQVAE1D forward. 256x256-tile MFMA GEMMs (128x64 per wave, 2-buffer
// pipelined), split-bf16 encoder+scores, plain bf16 decoder.
// N=16384, D=1024, H=1024, L=256, K=4096.
// out = [x_pred (N*D) f32 | z_discrete 0/1 f32 (N*K) | loss (1)]

#define MB (1024ULL * 1024ULL)

typedef __attribute__((ext_vector_type(8))) short s16x8;
typedef __attribute__((ext_vector_type(4))) float f32x4;

__device__ __forceinline__ ushort f2bf(float f) {
    unsigned u = __float_as_uint(f);
    u += 0x7fffu + ((u >> 16) & 1u);
    return (ushort)(u >> 16);
}
__device__ __forceinline__ float bf2f(ushort h) {
    return __uint_as_float(((unsigned)h) << 16);
}
__device__ __forceinline__ float gelu_f(float v) {
    return 0.5f * v * (1.0f + erff(v * 0.70710678118654752f));
}
__device__ __forceinline__ void gload16(const void* g, void* l) {
    __builtin_amdgcn_global_load_lds(
        (const __attribute__((address_space(1))) void*)g,
        (__attribute__((address_space(3))) void*)l, 16, 0, 0);
}

// ---------------------------------------------------------------------------
// f32 [R][K] -> hilo-packed bf16: row stride 2K ushorts, per 32-k slab:
// [32 hi | 32 lo].
__global__ __launch_bounds__(256)
void split_pack(const float* __restrict__ in, ushort* __restrict__ out,
                int R, int K)
{
    const int nch = R * (K >> 3);
    for (int i = blockIdx.x * 256 + threadIdx.x; i < nch; i += gridDim.x * 256) {
        const int row = i / (K >> 3);
        const int k8 = (i - row * (K >> 3)) * 8;
        const float4 v0 = *(const float4*)(in + (size_t)row * K + k8);
        const float4 v1 = *(const float4*)(in + (size_t)row * K + k8 + 4);
        float f[8] = {v0.x, v0.y, v0.z, v0.w, v1.x, v1.y, v1.z, v1.w};
        ushort h[8], l[8];
        #pragma unroll
        for (int j = 0; j < 8; j++) {
            h[j] = f2bf(f[j]);
            l[j] = f2bf(f[j] - bf2f(h[j]));
        }
        size_t o = (size_t)row * 2 * K + ((k8 >> 5) << 6) + (k8 & 31);
        *(ushort4*)(out + o)      = make_ushort4(h[0], h[1], h[2], h[3]);
        *(ushort4*)(out + o + 4)  = make_ushort4(h[4], h[5], h[6], h[7]);
        *(ushort4*)(out + o + 32) = make_ushort4(l[0], l[1], l[2], l[3]);
        *(ushort4*)(out + o + 36) = make_ushort4(l[4], l[5], l[6], l[7]);
    }
}

// W [Kd, Nn] f32 -> out [Nn][Kd]; PACK -> hilo-packed, else plain bf16.
template<bool PACK>
__global__ __launch_bounds__(256)
void transpose_cvt(const float* __restrict__ in, ushort* __restrict__ out,
                   int Kd, int Nn)
{
    __shared__ float tile[32][33];
    const int n0 = blockIdx.x * 32, k0 = blockIdx.y * 32;
    const int tx = threadIdx.x & 31, ty = threadIdx.x >> 5;
    #pragma unroll
    for (int r = 0; r < 4; r++)
        tile[ty + r * 8][tx] = in[(size_t)(k0 + ty + r * 8) * Nn + n0 + tx];
    __syncthreads();
    #pragma unroll
    for (int r = 0; r < 4; r++) {
        const float v = tile[tx][ty + r * 8];
        const int row = n0 + ty + r * 8, k = k0 + tx;
        if constexpr (PACK) {
            size_t o = (size_t)row * 2 * Kd + ((k >> 5) << 6) + (k & 31);
            ushort h = f2bf(v);
            out[o] = h;
            out[o + 32] = f2bf(v - bf2f(h));
        } else {
            out[(size_t)row * Kd + k] = f2bf(v);
        }
    }
}

// ||e_k||^2 per codebook row (L=256)
__global__ __launch_bounds__(64)
void colnorm(const float* __restrict__ pool, float* __restrict__ c)
{
    int r = blockIdx.x, lane = threadIdx.x;
    float4 v = *(const float4*)(pool + (size_t)r * 256 + lane * 4);
    float s = v.x * v.x + v.y * v.y + v.z * v.z + v.w * v.w;
    #pragma unroll
    for (int o = 32; o > 0; o >>= 1) s += __shfl_down(s, o);
    if (lane == 0) c[r] = s;
}

// ---------------------------------------------------------------------------
// Big MFMA GEMM: C[M,Nn] = A[M,Kd] @ B^T, B given as [Nn,Kd].
// Block tile 256x256, 512 threads = 8 waves (2x4), per-wave 128x64 output
// (8x4 fragments from 8+4 frag loads -> 2x LDS arithmetic intensity vs 64x64).
// 2 LDS buffers x 64KB, depth-1 prefetch: vmcnt(0) -> barrier -> STAGE(t+1)
// -> compute(t). XCD-bijective block swizzle (nwg % 8 == 0 on all launches).
// SPLIT: BK=32 hilo slab (3 MFMA/frag pair); plain: BK=64.
// EPI: 0=+bias, 1=gelu(+bias), 2=sigmoid(+bias)+SSE, 3=VQ argmin partials.
template<int EPI, bool SPLIT, bool PACKOUT>
__global__ __launch_bounds__(512, 2)
void gemm_big(const ushort* __restrict__ A, const ushort* __restrict__ B,
              const float* __restrict__ bias, int Kd, int Nn,
              int rsA, int rsB,                    // row strides in BYTES
              ushort* __restrict__ Cu, float* __restrict__ Cf,
              const float* __restrict__ xref, float* __restrict__ ssePartial,
              float* __restrict__ pval, int* __restrict__ pidx)
{
    extern __shared__ ushort smem[];
    constexpr int BUFS = 512 * 64;                  // 64KB per buffer

    const int tid = threadIdx.x;
    const int wave = tid >> 6, lane = tid & 63;

    const int nx = gridDim.x;
    const int nwg = nx * gridDim.y;
    const int orig = blockIdx.y * nx + blockIdx.x;
    const int wgid = (orig & 7) * (nwg >> 3) + (orig >> 3);
    const int bx = wgid % nx, by = wgid / nx;

    const int m0 = by * 256, n0 = bx * 256;
    const int wr = wave >> 2, wc = wave & 3;        // 2 x 4 wave grid
    const int fcol = lane & 15, kgrp = lane >> 4;
    const int NT = Kd / (SPLIT ? 32 : 64);

    const int srow = lane >> 3;                     // row within 8-row chunk
    const int sswz = ((lane & 7) ^ srow) << 4;      // swizzled src byte
    const char* Abase = (const char*)A + (size_t)m0 * rsA;
    const char* Bbase = (const char*)B + (size_t)n0 * rsB;

    f32x4 acc[8][4];
    #pragma unroll
    for (int m = 0; m < 8; m++)
        #pragma unroll
        for (int n = 0; n < 4; n++)
            acc[m][n] = (f32x4){0.f, 0.f, 0.f, 0.f};

    auto STAGE = [&](int buf, int t) {
        ushort* dst = smem + buf * BUFS;
        const size_t kb = (size_t)t * 128;
        #pragma unroll
        for (int g = 0; g < 4; g++) {
            const int rb = g * 64 + wave * 8;
            gload16(Abase + (size_t)(rb + srow) * rsA + kb + sswz, dst + rb * 64);
            gload16(Bbase + (size_t)(rb + srow) * rsB + kb + sswz,
                    dst + (256 + rb) * 64);
        }
    };
    auto LD = [&](int buf, int r, int u) -> s16x8 {
        return *(const s16x8*)(smem + buf * BUFS + r * 64 + ((u ^ (r & 7)) << 3));
    };

    STAGE(0, 0);
    for (int t = 0; t < NT; ++t) {
        asm volatile("s_waitcnt vmcnt(0)" ::: "memory");
        __builtin_amdgcn_s_barrier();
        if (t + 1 < NT) STAGE((t + 1) & 1, t + 1);
        const int buf = t & 1;
        if constexpr (SPLIT) {
            s16x8 bH[4], bL[4];
            #pragma unroll
            for (int n = 0; n < 4; n++) {
                const int r = 256 + wc * 64 + n * 16 + fcol;
                bH[n] = LD(buf, r, kgrp);
                bL[n] = LD(buf, r, 4 + kgrp);
            }
            #pragma unroll
            for (int h = 0; h < 2; h++) {
                s16x8 aH[4], aL[4];
                #pragma unroll
                for (int i = 0; i < 4; i++) {
                    const int r = wr * 128 + (h * 4 + i) * 16 + fcol;
                    aH[i] = LD(buf, r, kgrp);
                    aL[i] = LD(buf, r, 4 + kgrp);
                }
                __builtin_amdgcn_s_setprio(1);
                #pragma unroll
                for (int i = 0; i < 4; i++)
                    #pragma unroll
                    for (int n = 0; n < 4; n++) {
                        acc[h * 4 + i][n] = __builtin_amdgcn_mfma_f32_16x16x32_bf16(
                            aH[i], bH[n], acc[h * 4 + i][n], 0, 0, 0);
                        acc[h * 4 + i][n] = __builtin_amdgcn_mfma_f32_16x16x32_bf16(
                            aH[i], bL[n], acc[h * 4 + i][n], 0, 0, 0);
                        acc[h * 4 + i][n] = __builtin_amdgcn_mfma_f32_16x16x32_bf16(
                            aL[i], bH[n], acc[h * 4 + i][n], 0, 0, 0);
                    }
                __builtin_amdgcn_s_setprio(0);
            }
        } else {
            s16x8 b2[4][2];
            #pragma unroll
            for (int n = 0; n < 4; n++) {
                const int r = 256 + wc * 64 + n * 16 + fcol;
                #pragma unroll
                for (int ks = 0; ks < 2; ks++) b2[n][ks] = LD(buf, r, ks * 4 + kgrp);
            }
            #pragma unroll
            for (int h = 0; h < 2; h++) {
                s16x8 a2[4][2];
                #pragma unroll
                for (int i = 0; i < 4; i++) {
                    const int r = wr * 128 + (h * 4 + i) * 16 + fcol;
                    #pragma unroll
                    for (int ks = 0; ks < 2; ks++) a2[i][ks] = LD(buf, r, ks * 4 + kgrp);
                }
                __builtin_amdgcn_s_setprio(1);
                #pragma unroll
                for (int i = 0; i < 4; i++)
                    #pragma unroll
                    for (int n = 0; n < 4; n++)
                        #pragma unroll
                        for (int ks = 0; ks < 2; ks++)
                            acc[h * 4 + i][n] = __builtin_amdgcn_mfma_f32_16x16x32_bf16(
                                a2[i][ks], b2[n][ks], acc[h * 4 + i][n], 0, 0, 0);
                __builtin_amdgcn_s_setprio(0);
            }
        }
    }
    __builtin_amdgcn_sched_barrier(0);

    // ------------------------------ epilogue ------------------------------
    int colg[4];
    float bcol[4];
    #pragma unroll
    for (int n = 0; n < 4; n++) {
        colg[n] = n0 + wc * 64 + n * 16 + fcol;
        bcol[n] = bias[colg[n]];
    }

    if constexpr (EPI == 0 || EPI == 1) {
        #pragma unroll
        for (int m = 0; m < 8; m++)
            #pragma unroll
            for (int v = 0; v < 4; v++) {
                const int row = m0 + wr * 128 + m * 16 + kgrp * 4 + v;
                #pragma unroll
                for (int n = 0; n < 4; n++) {
                    float val = acc[m][n][v] + bcol[n];
                    if (EPI == 1) val = gelu_f(val);
                    if constexpr (PACKOUT) {
                        size_t o = (size_t)row * 2 * Nn + ((colg[n] >> 5) << 6) + (colg[n] & 31);
                        ushort h = f2bf(val);
                        Cu[o] = h;
                        Cu[o + 32] = f2bf(val - bf2f(h));
                    } else {
                        Cu[(size_t)row * Nn + colg[n]] = f2bf(val);
                    }
                }
            }
    } else if constexpr (EPI == 2) {
        float lsse = 0.0f;
        #pragma unroll
        for (int m = 0; m < 8; m++)
            #pragma unroll
            for (int v = 0; v < 4; v++) {
                const int row = m0 + wr * 128 + m * 16 + kgrp * 4 + v;
                const size_t rb = (size_t)row * Nn;
                #pragma unroll
                for (int n = 0; n < 4; n++) {
                    float val = acc[m][n][v] + bcol[n];
                    val = 1.0f / (1.0f + expf(-val));
                    __builtin_nontemporal_store(val, &Cf[rb + colg[n]]);
                    float d = xref[rb + colg[n]] - val;
                    lsse += d * d;
                }
            }
        __syncthreads();
        float* red = (float*)smem;
        red[tid] = lsse;
        __syncthreads();
        for (int s = 256; s > 0; s >>= 1) {
            if (tid < s) red[tid] += red[tid + s];
            __syncthreads();
        }
        if (tid == 0) ssePartial[by * nx + bx] = red[0];
    } else if constexpr (EPI == 3) {
        __syncthreads();
        float* sv = (float*)smem;            // [4][256]
        int*   si = (int*)(sv + 1024);
        #pragma unroll
        for (int m = 0; m < 8; m++)
            #pragma unroll
            for (int v = 0; v < 4; v++) {
                float best = INFINITY;
                int bidx = 0x7fffffff;
                #pragma unroll
                for (int n = 0; n < 4; n++) {
                    float sc = bcol[n] - 2.0f * acc[m][n][v];
                    if (sc < best || (sc == best && colg[n] < bidx)) { best = sc; bidx = colg[n]; }
                }
                #pragma unroll
                for (int d = 1; d < 16; d <<= 1) {
                    float ov = __shfl_xor(best, d, 64);
                    int   oi = __shfl_xor(bidx, d, 64);
                    if (ov < best || (ov == best && oi < bidx)) { best = ov; bidx = oi; }
                }
                if (fcol == 0) {
                    const int rl = wr * 128 + m * 16 + kgrp * 4 + v;
                    sv[wc * 256 + rl] = best;
                    si[wc * 256 + rl] = bidx;
                }
            }
        __syncthreads();
        if (tid < 256) {
            float v0 = sv[tid];
            int   i0 = si[tid];
            #pragma unroll
            for (int c = 1; c < 4; c++) {
                float v1 = sv[c * 256 + tid];
                int   i1 = si[c * 256 + tid];
                if (v1 < v0 || (v1 == v0 && i1 < i0)) { v0 = v1; i0 = i1; }
            }
            pval[(size_t)(m0 + tid) * nx + bx] = v0;
            pidx[(size_t)(m0 + tid) * nx + bx] = i0;
        }
    }
}

// ---------------------------------------------------------------------------
// enc3 GEMM (r5-proven structure): 128x128 tile, waves 2x4 (64x32/wave),
// 3 buffers, distance-2 prefetch, counted vmcnt(4). SPLIT, PACKOUT, EPI=0.
__global__ __launch_bounds__(512, 2)
void gemm_enc3(const ushort* __restrict__ A, const ushort* __restrict__ B,
               const float* __restrict__ bias, int Kd, int Nn,
               int rsA, int rsB, ushort* __restrict__ Cu)
{
    extern __shared__ ushort smem[];
    constexpr int BUFS = 256 * 64;                  // 32KB per buffer

    const int tid = threadIdx.x;
    const int wave = tid >> 6, lane = tid & 63;

    const int nx = gridDim.x;
    const int nwg = nx * gridDim.y;
    const int orig = blockIdx.y * nx + blockIdx.x;
    const int wgid = (orig & 7) * (nwg >> 3) + (orig >> 3);
    const int bx = wgid % nx, by = wgid / nx;

    const int m0 = by * 128, n0 = bx * 128;
    const int wr = wave >> 2, wc = wave & 3;
    const int fcol = lane & 15, kgrp = lane >> 4;
    const int NT = Kd / 32;

    const int srow = lane >> 3;
    const int sswz = ((lane & 7) ^ srow) << 4;
    const char* Abase = (const char*)A + (size_t)m0 * rsA;
    const char* Bbase = (const char*)B + (size_t)n0 * rsB;

    f32x4 acc[4][2];
    #pragma unroll
    for (int m = 0; m < 4; m++)
        #pragma unroll
        for (int n = 0; n < 2; n++)
            acc[m][n] = (f32x4){0.f, 0.f, 0.f, 0.f};

    auto STAGE = [&](int buf, int t) {
        ushort* dst = smem + buf * BUFS;
        const size_t kb = (size_t)t * 128;
        #pragma unroll
        for (int g = 0; g < 2; g++) {
            const int rb = g * 64 + wave * 8;
            gload16(Abase + (size_t)(rb + srow) * rsA + kb + sswz, dst + rb * 64);
            gload16(Bbase + (size_t)(rb + srow) * rsB + kb + sswz,
                    dst + (128 + rb) * 64);
        }
    };
    auto LD = [&](int buf, int r, int u) -> s16x8 {
        return *(const s16x8*)(smem + buf * BUFS + r * 64 + ((u ^ (r & 7)) << 3));
    };

    STAGE(0, 0);
    STAGE(1, 1);
    for (int t = 0; t < NT; ++t) {
        if (t + 1 < NT) asm volatile("s_waitcnt vmcnt(4)" ::: "memory");
        else            asm volatile("s_waitcnt vmcnt(0)" ::: "memory");
        __builtin_amdgcn_s_barrier();
        if (t + 2 < NT) STAGE((t + 2) % 3, t + 2);
        const int buf = t % 3;
        s16x8 aH[4], aL[4], bH[2], bL[2];
        #pragma unroll
        for (int m = 0; m < 4; m++) {
            const int r = wr * 64 + m * 16 + fcol;
            aH[m] = LD(buf, r, kgrp);
            aL[m] = LD(buf, r, 4 + kgrp);
        }
        #pragma unroll
        for (int n = 0; n < 2; n++) {
            const int r = 128 + wc * 32 + n * 16 + fcol;
            bH[n] = LD(buf, r, kgrp);
            bL[n] = LD(buf, r, 4 + kgrp);
        }
        __builtin_amdgcn_s_setprio(1);
        #pragma unroll
        for (int m = 0; m < 4; m++)
            #pragma unroll
            for (int n = 0; n < 2; n++) {
                acc[m][n] = __builtin_amdgcn_mfma_f32_16x16x32_bf16(aH[m], bH[n], acc[m][n], 0, 0, 0);
                acc[m][n] = __builtin_amdgcn_mfma_f32_16x16x32_bf16(aH[m], bL[n], acc[m][n], 0, 0, 0);
                acc[m][n] = __builtin_amdgcn_mfma_f32_16x16x32_bf16(aL[m], bH[n], acc[m][n], 0, 0, 0);
            }
        __builtin_amdgcn_s_setprio(0);
    }
    __builtin_amdgcn_sched_barrier(0);

    #pragma unroll
    for (int n = 0; n < 2; n++) {
        const int col = n0 + wc * 32 + n * 16 + fcol;
        const float bc = bias[col];
        #pragma unroll
        for (int m = 0; m < 4; m++)
            #pragma unroll
            for (int v = 0; v < 4; v++) {
                const int row = m0 + wr * 64 + m * 16 + kgrp * 4 + v;
                float val = acc[m][n][v] + bc;
                size_t o = (size_t)row * 2 * Nn + ((col >> 5) << 6) + (col & 31);
                ushort h = f2bf(val);
                Cu[o] = h;
                Cu[o + 32] = f2bf(val - bf2f(h));
            }
    }
}

// ---------------------------------------------------------------------------
// 4 rows per block: reduce nblk block partials -> kbest; one-hot (nontemporal);
// gather z_q; VQ partial.
__global__ __launch_bounds__(256)
void argmin_final(const float* __restrict__ pval, const int* __restrict__ pidx,
                  int nblk, const ushort* __restrict__ zEp,
                  const float* __restrict__ pool,
                  float* __restrict__ zdisc, ushort* __restrict__ zq,
                  float* __restrict__ vqP)
{
    const int t = threadIdx.x;
    const int r = blockIdx.x * 4 + (t >> 6);
    const int l = t & 63;

    float best = INFINITY;
    int bi = 0x7fffffff;
    if (l < nblk) {
        best = pval[(size_t)r * nblk + l];
        bi = pidx[(size_t)r * nblk + l];
    }
    #pragma unroll
    for (int d = 32; d > 0; d >>= 1) {
        float ov = __shfl_xor(best, d, 64);
        int   oi = __shfl_xor(bi, d, 64);
        if (ov < best || (ov == best && oi < bi)) { best = ov; bi = oi; }
    }
    const int kbest = bi;

    f32x4* zrow = (f32x4*)(zdisc + (size_t)r * 4096);
    #pragma unroll
    for (int it = 0; it < 16; it++) {
        const int j = it * 64 + l;
        f32x4 o = (f32x4){0.f, 0.f, 0.f, 0.f};
        if ((kbest >> 2) == j) o[kbest & 3] = 1.0f;
        __builtin_nontemporal_store(o, &zrow[j]);
    }

    const float4 pz = *(const float4*)(pool + (size_t)kbest * 256 + l * 4);
    *(ushort4*)(zq + (size_t)r * 256 + l * 4) =
        make_ushort4(f2bf(pz.x), f2bf(pz.y), f2bf(pz.z), f2bf(pz.w));
    const size_t zo = (size_t)r * 512 + (((l * 4) >> 5) << 6) + ((l * 4) & 31);
    const ushort4 zh = *(const ushort4*)(zEp + zo);
    const ushort4 zl = *(const ushort4*)(zEp + zo + 32);
    float d0 = bf2f(zh.x) + bf2f(zl.x) - pz.x;
    float d1 = bf2f(zh.y) + bf2f(zl.y) - pz.y;
    float d2 = bf2f(zh.z) + bf2f(zl.z) - pz.z;
    float d3 = bf2f(zh.w) + bf2f(zl.w) - pz.w;
    float s = d0 * d0 + d1 * d1 + d2 * d2 + d3 * d3;
    #pragma unroll
    for (int o = 32; o > 0; o >>= 1) s += __shfl_xor(s, o, 64);
    if (l == 0) vqP[r] = s;
}

__global__ __launch_bounds__(256)
void loss_final(const float* __restrict__ sseP, int nP,
                const float* __restrict__ vqP, int nV,
                float* __restrict__ out)
{
    int tid = threadIdx.x;
    float sx = 0.0f, svq = 0.0f;
    for (int i = tid; i < nP; i += 256) sx += sseP[i];
    for (int i = tid; i < nV; i += 256) svq += vqP[i];
    __shared__ float a[256], b[256];
    a[tid] = sx; b[tid] = svq;
    __syncthreads();
    for (int s = 128; s > 0; s >>= 1) {
        if (tid < s) { a[tid] += a[tid + s]; b[tid] += b[tid + s]; }
        __syncthreads();
    }
    if (tid == 0) out[0] = (a[0] + 1.25f * b[0]) / 16384.0f;
}

// ---------------------------------------------------------------------------
extern "C" void kernel_launch(void* const* d_in, const int* in_sizes, int n_in,
                              void* d_out, int out_size, void* d_ws, size_t ws_size,
                              hipStream_t stream)
{
    const float* x    = (const float*)d_in[0];
    const float* pool = (const float*)d_in[1];
    const float* ew1  = (const float*)d_in[2];
    const float* eb1  = (const float*)d_in[3];
    const float* ew2  = (const float*)d_in[4];
    const float* eb2  = (const float*)d_in[5];
    const float* ew3  = (const float*)d_in[6];
    const float* eb3  = (const float*)d_in[7];
    const float* dw1  = (const float*)d_in[8];
    const float* db1  = (const float*)d_in[9];
    const float* dw2  = (const float*)d_in[10];
    const float* db2  = (const float*)d_in[11];
    const float* dw3  = (const float*)d_in[12];
    const float* db3  = (const float*)d_in[13];

    const int N = 16384, D = 1024, H = 1024, L = 256, K = 4096;

    float* out   = (float*)d_out;
    float* xpred = out;
    float* zdisc = out + (size_t)N * D;
    float* lossp = zdisc + (size_t)N * K;

    char* ws = (char*)d_ws;
    ushort* xp    = (ushort*)(ws + 0 * MB);    // 64MB packed x
    ushort* h1p   = (ushort*)(ws + 64 * MB);   // 64MB
    ushort* h2p   = (ushort*)(ws + 128 * MB);  // 64MB
    ushort* zEp   = (ushort*)(ws + 192 * MB);  // 16MB
    ushort* zq    = (ushort*)(ws + 208 * MB);  // 8MB plain bf16
    ushort* poolp = (ushort*)(ws + 216 * MB);  // 4MB
    ushort* w1p   = (ushort*)(ws + 220 * MB);  // 4MB
    ushort* w2p   = (ushort*)(ws + 224 * MB);  // 4MB
    ushort* w3p   = (ushort*)(ws + 228 * MB);  // 1MB
    ushort* v1    = (ushort*)(ws + 229 * MB);  // 0.5MB plain
    ushort* v2    = (ushort*)(ws + 230 * MB);  // 2MB
    ushort* v3    = (ushort*)(ws + 232 * MB);  // 2MB
    ushort* h3    = (ushort*)(ws + 240 * MB);  // 32MB plain
    ushort* h4    = (ushort*)(ws + 272 * MB);  // 32MB
    float*  cn    = (float*)(ws + 304 * MB);   // 16KB
    float*  pv    = (float*)(ws + 305 * MB);   // 1MB
    int*    pi    = (int*)(ws + 307 * MB);     // 1MB
    float*  vqP   = (float*)(ws + 309 * MB);   // 64KB
    float*  sxP   = (float*)(ws + 310 * MB);   // 4KB

    const int SH_BIG = 2 * (512 * 64) * 2;     // 131072 B
    const int SH_E3  = 3 * (256 * 64) * 2;     // 98304 B
    (void)hipFuncSetAttribute((const void*)gemm_big<1, true, true>,
        hipFuncAttributeMaxDynamicSharedMemorySize, SH_BIG);
    (void)hipFuncSetAttribute((const void*)gemm_big<3, true, false>,
        hipFuncAttributeMaxDynamicSharedMemorySize, SH_BIG);
    (void)hipFuncSetAttribute((const void*)gemm_big<1, false, false>,
        hipFuncAttributeMaxDynamicSharedMemorySize, SH_BIG);
    (void)hipFuncSetAttribute((const void*)gemm_big<2, false, false>,
        hipFuncAttributeMaxDynamicSharedMemorySize, SH_BIG);
    (void)hipFuncSetAttribute((const void*)gemm_enc3,
        hipFuncAttributeMaxDynamicSharedMemorySize, SH_E3);

    dim3 blk(256), gblk(512);

    // prep
    split_pack<<<2048, blk, 0, stream>>>(x, xp, N, D);
    split_pack<<<512, blk, 0, stream>>>(pool, poolp, K, L);
    colnorm<<<K, 64, 0, stream>>>(pool, cn);
    transpose_cvt<true><<<dim3(H / 32, D / 32), blk, 0, stream>>>(ew1, w1p, D, H);
    transpose_cvt<true><<<dim3(H / 32, H / 32), blk, 0, stream>>>(ew2, w2p, H, H);
    transpose_cvt<true><<<dim3(L / 32, H / 32), blk, 0, stream>>>(ew3, w3p, H, L);
    transpose_cvt<false><<<dim3(H / 32, L / 32), blk, 0, stream>>>(dw1, v1, L, H);
    transpose_cvt<false><<<dim3(H / 32, H / 32), blk, 0, stream>>>(dw2, v2, H, H);
    transpose_cvt<false><<<dim3(D / 32, H / 32), blk, 0, stream>>>(dw3, v3, H, D);

    // encoder (split, packed in/out)
    gemm_big<1, true, true><<<dim3(H / 256, N / 256), gblk, SH_BIG, stream>>>(
        xp, w1p, eb1, D, H, 2 * D * 2, 2 * D * 2, h1p, nullptr, nullptr, nullptr, nullptr, nullptr);
    gemm_big<1, true, true><<<dim3(H / 256, N / 256), gblk, SH_BIG, stream>>>(
        h1p, w2p, eb2, H, H, 2 * H * 2, 2 * H * 2, h2p, nullptr, nullptr, nullptr, nullptr, nullptr);
    // enc3: 128-tile kernel -> 256 blocks (full GPU; L=256 cols only)
    gemm_enc3<<<dim3(L / 128, N / 128), gblk, SH_E3, stream>>>(
        h2p, w3p, eb3, H, L, 2 * H * 2, 2 * H * 2, zEp);

    // VQ scores + fused per-block argmin (split)
    gemm_big<3, true, false><<<dim3(K / 256, N / 256), gblk, SH_BIG, stream>>>(
        zEp, poolp, cn, L, K, 2 * L * 2, 2 * L * 2, nullptr, nullptr, nullptr, nullptr, pv, pi);

    argmin_final<<<N / 4, blk, 0, stream>>>(pv, pi, K / 256, zEp, pool, zdisc, zq, vqP);

    // decoder (plain bf16)
    gemm_big<1, false, false><<<dim3(H / 256, N / 256), gblk, SH_BIG, stream>>>(
        zq, v1, db1, L, H, L * 2, L * 2, h3, nullptr, nullptr, nullptr, nullptr, nullptr);
    gemm_big<1, false, false><<<dim3(H / 256, N / 256), gblk, SH_BIG, stream>>>(
        h3, v2, db2, H, H, H * 2, H * 2, h4, nullptr, nullptr, nullptr, nullptr, nullptr);
    gemm_big<2, false, false><<<dim3(D / 256, N / 256), gblk, SH_BIG, stream>>>(
        h4, v3, db3, H, D, H * 2, H * 2, nullptr, xpred, x, sxP, nullptr, nullptr);

    loss_final<<<1, blk, 0, stream>>>(sxP, (D / 256) * (N / 256), vqP, N, lossp);
}